// Round 9
// baseline (184.132 us; speedup 1.0000x reference)
//
#include <hip/hip_runtime.h>
#include <math.h>

// Problem constants
#define S_DIM 128
#define Q_DIM 64
#define P_DIM 64
#define D_DIM 256
#define NQ (S_DIM * Q_DIM)   // 8192 question rows
#define NS (S_DIM * P_DIM)   // 8192 sentence rows

typedef __attribute__((ext_vector_type(4))) float f32x4;
typedef __attribute__((ext_vector_type(8))) short bf16x8;
typedef __attribute__((ext_vector_type(8))) _Float16 f16x8;
typedef __attribute__((ext_vector_type(4))) _Float16 f16x4;

// ---------- helpers ----------
__device__ __forceinline__ unsigned short f2bf(float f) {
    unsigned int u = __float_as_uint(f);
    u = (u + 0x7fffu + ((u >> 16) & 1u)) >> 16;   // RNE (no NaN inputs here)
    return (unsigned short)u;
}
__device__ __forceinline__ float bf2f(unsigned short h) {
    return __uint_as_float(((unsigned int)h) << 16);
}

// ws layout:
//  floats [0, 8192)  total_exp (zeroed)
//  floats [8192,8320) den  [8320,8448) num  [8448,8450) loss_acc  [8452] ticket
//  halves from (ws+8704 floats):
//    qf [0,2097152)  sf [2097152,4194304)  stf [4194304,4227072)   (fp16, scaled)
//    q_hi @4718592  q_lo @6815744  s_hi @8912896  s_lo @11010048   (bf16, scaled)

// One wave per row: inv-norm; write fp16 scaled row (all tensors) and bf16
// hi/lo split (q,s only — consumed by the precision-sensitive qs2 pos path).
// exp(sim/TEMP) == exp2(dot of scaled rows) with per-row folded scale.
__global__ __launch_bounds__(256) void normsplit_kernel(
    const float* __restrict__ qm, const float* __restrict__ sm,
    const float* __restrict__ st, float* __restrict__ zero_region,
    _Float16* __restrict__ qf, _Float16* __restrict__ sf, _Float16* __restrict__ stf,
    unsigned short* __restrict__ q_hi, unsigned short* __restrict__ q_lo,
    unsigned short* __restrict__ s_hi, unsigned short* __restrict__ s_lo) {
    if (blockIdx.x < 34) {
        int i = blockIdx.x * 256 + threadIdx.x;
        if (i < 8456) zero_region[i] = 0.0f;
    }
    int row = blockIdx.x * 4 + (threadIdx.x >> 6);
    int lane = threadIdx.x & 63;
    const float* src;
    _Float16* fdst;
    unsigned short *hi = nullptr, *lo = nullptr;
    int r;
    if (row < NQ) {
        r = row; src = qm + (size_t)r * D_DIM; fdst = qf + (size_t)r * D_DIM;
        hi = q_hi + (size_t)r * D_DIM; lo = q_lo + (size_t)r * D_DIM;
    } else if (row < NQ + NS) {
        r = row - NQ; src = sm + (size_t)r * D_DIM; fdst = sf + (size_t)r * D_DIM;
        hi = s_hi + (size_t)r * D_DIM; lo = s_lo + (size_t)r * D_DIM;
    } else if (row < NQ + NS + S_DIM) {
        r = row - NQ - NS; src = st + (size_t)r * D_DIM; fdst = stf + (size_t)r * D_DIM;
    } else return;

    float4 v = reinterpret_cast<const float4*>(src)[lane];
    float ss = v.x * v.x + v.y * v.y + v.z * v.z + v.w * v.w;
    #pragma unroll
    for (int off = 32; off; off >>= 1) ss += __shfl_xor(ss, off);
    float inv = 1.0f / fmaxf(sqrtf(ss), 1e-12f);

    const float CF = sqrtf((1.0f / 0.07f) * 1.44269504088896f);
    float sc = inv * CF;
    float x[4] = {v.x * sc, v.y * sc, v.z * sc, v.w * sc};

    f16x4 fv;
    #pragma unroll
    for (int e = 0; e < 4; e++) fv[e] = (_Float16)x[e];
    reinterpret_cast<f16x4*>(fdst)[lane] = fv;

    if (hi) {
        ushort4 h, l;
        unsigned short* hp = &h.x; unsigned short* lp = &l.x;
        #pragma unroll
        for (int e = 0; e < 4; e++) {
            unsigned short hh = f2bf(x[e]);
            hp[e] = hh;
            lp[e] = f2bf(x[e] - bf2f(hh));
        }
        reinterpret_cast<ushort4*>(hi)[lane] = h;
        reinterpret_cast<ushort4*>(lo)[lane] = l;
    }
}

// L2-direct streaming fp16 MFMA GEMM + fused exp2/rowsum. NO LDS, NO barriers.
// 544 blocks x 256 threads (4 waves). Each wave owns 64 output rows: A-frags
// for the FULL K=256 live in 128 VGPRs; B-fragments are read straight from
// the XCD-local L2 panel (512 cols x 512 B = 256 KB, 2 panels/XCD).
//  blocks [32,544): A-pass. wave = (rowgroup rg of 64 q-rows) x (panel of 512
//    s-cols = 16 col-groups of 32). 2048 waves = 128 rg x 16 panels; exactly
//    2 blocks/CU (launch_bounds(256,2), ~212 VGPR) -> no tail.
//  blocks [0,32): C-pass. wave = 64 st-rows x 128 q-cols (4 col-groups);
//    dispatched first so the short blocks backfill.
// Per col-group: 8 k-chunks x {2 global_load_dwordx4 + 8 MFMA}; 8 independent
// acc chains + 16 independent loads give ILP; 8 waves/CU give TLP. Loads never
// meet a barrier — the compiler's own s_waitcnt is the only sync.
// Epilogue per group in registers; atomics once per wave at the end.
__global__ __launch_bounds__(256, 2) void mfma_l2stream_kernel(
    const _Float16* __restrict__ qf, const _Float16* __restrict__ sf,
    const _Float16* __restrict__ stf,
    float* __restrict__ total_exp, float* __restrict__ den, float* __restrict__ num) {
    const int tid = threadIdx.x;
    const int w = tid >> 6, lane = tid & 63;
    const int lane15 = lane & 15, kg = lane >> 4;

    const bool cpass = (blockIdx.x < 32);
    const _Float16* A;
    const _Float16* B;
    int row0, colbase, nG;
    if (cpass) {
        const int idx = (int)blockIdx.x * 4 + w;   // 0..127
        A = stf; B = qf;
        row0 = (idx >> 6) * 64;                    // st rowgroup 0/1
        colbase = (idx & 63) * 128;                // 64 q-col panels of 128
        nG = 4;
    } else {
        const int b2 = (int)blockIdx.x - 32;       // 0..511
        A = qf; B = sf;
        const int panel = (b2 & 7) * 2 + (w & 1);  // 16 s-col panels of 512
        const int rg = (b2 >> 3) * 2 + (w >> 1);   // 128 q-rowgroups of 64
        row0 = rg * 64;
        colbase = panel * 512;
        nG = 16;
    }

    // A fragments: this wave's 64 rows x K=256, in registers (128 VGPR).
    // 16x16x32 A layout: row = lane&15, k = (lane>>4)*8 + e (+ c*32 chunks).
    f16x8 af[4][8];
    {
        const _Float16* ap = A + (((size_t)(row0 + lane15)) << 8) + kg * 8;
        #pragma unroll
        for (int mb = 0; mb < 4; mb++)
            #pragma unroll
            for (int c = 0; c < 8; c++)
                af[mb][c] = *reinterpret_cast<const f16x8*>(ap + mb * 16 * 256 + c * 32);
    }

    float rs[4][4] = {{0.f}}, nm[4][4] = {{0.f}};
    #pragma unroll
    for (int mb = 0; mb < 4; mb++)
        #pragma unroll
        for (int j = 0; j < 4; j++) { rs[mb][j] = 0.f; nm[mb][j] = 0.f; }

    const _Float16* bp = B + (((size_t)(colbase + lane15)) << 8) + kg * 8;

    for (int ct = 0; ct < nG; ct++) {
        f32x4 acc[4][2];
        #pragma unroll
        for (int mb = 0; mb < 4; mb++) {
            acc[mb][0] = (f32x4){0.f, 0.f, 0.f, 0.f};
            acc[mb][1] = (f32x4){0.f, 0.f, 0.f, 0.f};
        }
        const _Float16* bpc = bp + (size_t)ct * 32 * 256;
        #pragma unroll
        for (int c = 0; c < 8; c++) {
            f16x8 bf0 = *reinterpret_cast<const f16x8*>(bpc + c * 32);
            f16x8 bf1 = *reinterpret_cast<const f16x8*>(bpc + 16 * 256 + c * 32);
            #pragma unroll
            for (int mb = 0; mb < 4; mb++) {
                acc[mb][0] = __builtin_amdgcn_mfma_f32_16x16x32_f16(af[mb][c], bf0, acc[mb][0], 0, 0, 0);
                acc[mb][1] = __builtin_amdgcn_mfma_f32_16x16x32_f16(af[mb][c], bf1, acc[mb][1], 0, 0, 0);
            }
        }
        // Per-group epilogue (C/D 16x16: col = lane&15, row = (lane>>4)*4+j).
        #pragma unroll
        for (int mb = 0; mb < 4; mb++)
            #pragma unroll
            for (int j = 0; j < 4; j++) {
                float e0 = exp2f(acc[mb][0][j]);
                float e1 = exp2f(acc[mb][1][j]);
                rs[mb][j] += e0 + e1;
                if (cpass) {
                    const int grow = row0 + mb * 16 + kg * 4 + j;
                    const int c0 = colbase + ct * 32 + lane15;
                    if ((c0 >> 6) == grow) nm[mb][j] += e0;
                    if (((c0 + 16) >> 6) == grow) nm[mb][j] += e1;
                }
            }
    }

    // Reduce over the 16-lane col group; one atomic per row per wave.
    #pragma unroll
    for (int mb = 0; mb < 4; mb++)
        #pragma unroll
        for (int j = 0; j < 4; j++) {
            float v = rs[mb][j], u = nm[mb][j];
            #pragma unroll
            for (int off = 1; off < 16; off <<= 1) {
                v += __shfl_xor(v, off);
                if (cpass) u += __shfl_xor(u, off);
            }
            if (lane15 == 0) {
                const int grow = row0 + mb * 16 + kg * 4 + j;
                if (cpass) {
                    atomicAdd(&den[grow], v);
                    atomicAdd(&num[grow], u);
                } else {
                    atomicAdd(&total_exp[grow], v);
                }
            }
        }
}

// qs_loss + finalize. 256 blocks x 128 threads; block = half a section.
// pos/own_exp recomputed in bf16x3 (precision-sensitive path), straight from
// L2; all 16 A-frags preloaded for ILP. Last block (ticket) finalizes.
__global__ __launch_bounds__(128) void qs2_kernel(
    const unsigned short* __restrict__ q_hi, const unsigned short* __restrict__ q_lo,
    const unsigned short* __restrict__ s_hi, const unsigned short* __restrict__ s_lo,
    const float* __restrict__ total_exp, const float* __restrict__ den,
    const float* __restrict__ num, double* __restrict__ loss_acc,
    unsigned int* __restrict__ ticket, float* __restrict__ out) {
    const int s = blockIdx.x >> 1;
    const int tid = threadIdx.x;
    const int wid2 = ((blockIdx.x & 1) << 1) + (tid >> 6);   // 0..3 within section
    const int lane = tid & 63;
    __shared__ double wsum[2];
    __shared__ float w2[2];
    __shared__ unsigned int winner_s;

    const int arow = s * 64 + wid2 * 16 + (lane & 15);
    const int koff = (lane >> 4) * 8;

    bf16x8 ah[8], al[8];
    #pragma unroll
    for (int k8 = 0; k8 < 8; k8++) {
        ah[k8] = *reinterpret_cast<const bf16x8*>(&q_hi[(size_t)arow * D_DIM + k8 * 32 + koff]);
        al[k8] = *reinterpret_cast<const bf16x8*>(&q_lo[(size_t)arow * D_DIM + k8 * 32 + koff]);
    }

    f32x4 acc[4];
    #pragma unroll
    for (int n = 0; n < 4; n++) acc[n] = (f32x4){0.f, 0.f, 0.f, 0.f};
    #pragma unroll
    for (int n = 0; n < 4; n++) {
        const int brow = s * 64 + n * 16 + (lane & 15);
        #pragma unroll
        for (int k8 = 0; k8 < 8; k8++) {
            bf16x8 bh = *reinterpret_cast<const bf16x8*>(&s_hi[(size_t)brow * D_DIM + k8 * 32 + koff]);
            bf16x8 bl = *reinterpret_cast<const bf16x8*>(&s_lo[(size_t)brow * D_DIM + k8 * 32 + koff]);
            acc[n] = __builtin_amdgcn_mfma_f32_16x16x32_bf16(ah[k8], bh, acc[n], 0, 0, 0);
            acc[n] = __builtin_amdgcn_mfma_f32_16x16x32_bf16(ah[k8], bl, acc[n], 0, 0, 0);
            acc[n] = __builtin_amdgcn_mfma_f32_16x16x32_bf16(al[k8], bh, acc[n], 0, 0, 0);
        }
    }

    const float term2 = expf(-1.0f / 0.07f) * (float)(NS - 1);
    double lacc = 0.0;
    #pragma unroll
    for (int j = 0; j < 4; j++) {
        float e[4];
        float part = 0.0f;
        #pragma unroll
        for (int n = 0; n < 4; n++) { e[n] = exp2f(acc[n][j]); part += e[n]; }
        #pragma unroll
        for (int off = 1; off < 16; off <<= 1) part += __shfl_xor(part, off);
        const int trow = s * 64 + wid2 * 16 + (lane >> 4) * 4 + j;
        const float neg = total_exp[trow] - part;
        #pragma unroll
        for (int n = 0; n < 4; n++) {
            float posv = e[n];
            float t1 = fmaf(-0.1f, posv, neg / 0.9f);
            float Ng = fmaxf(fmaxf(t1, term2), 1e-8f);
            lacc += (double)(-logf(posv / (posv + Ng)));
        }
    }
    #pragma unroll
    for (int off = 1; off < 64; off <<= 1) lacc += __shfl_xor(lacc, off);
    if (lane == 0) wsum[tid >> 6] = lacc;
    __syncthreads();
    if (tid == 0) {
        atomicAdd(loss_acc, wsum[0] + wsum[1]);
        __threadfence();
        winner_s = atomicAdd(ticket, 1u);
    }
    __syncthreads();
    if (winner_s == 255) {
        __threadfence();   // acquire: all other blocks' loss atomics visible
        float l = -logf(num[tid] / den[tid]);   // tid = 0..127 = section
        #pragma unroll
        for (int off = 1; off < 64; off <<= 1) l += __shfl_xor(l, off);
        if ((tid & 63) == 0) w2[tid >> 6] = l;
        __syncthreads();
        if (tid == 0) out[0] = (float)(loss_acc[0] + (double)(w2[0] + w2[1]));
        // at_loss = -log(x/x) = 0 exactly; omitted.
    }
}

extern "C" void kernel_launch(void* const* d_in, const int* in_sizes, int n_in,
                              void* d_out, int out_size, void* d_ws, size_t ws_size,
                              hipStream_t stream) {
    const float* st = (const float*)d_in[1];   // [128,256]
    const float* qm = (const float*)d_in[2];   // [128,64,256]
    const float* sm = (const float*)d_in[3];   // [128,64,256]

    float* ws        = (float*)d_ws;
    float* total_exp = ws;
    float* den       = ws + 8192;
    float* num       = ws + 8320;
    double* loss_acc = (double*)(ws + 8448);
    unsigned int* ticket = (unsigned int*)(ws + 8452);
    _Float16* fbase = (_Float16*)(ws + 8704);
    _Float16* qf  = fbase;
    _Float16* sf  = fbase + 2097152;
    _Float16* stf = fbase + 4194304;
    unsigned short* b16 = (unsigned short*)fbase;
    unsigned short* q_hi = b16 + 4718592;
    unsigned short* q_lo = b16 + 6815744;
    unsigned short* s_hi = b16 + 8912896;
    unsigned short* s_lo = b16 + 11010048;
    float* out = (float*)d_out;

    // 1: zero accumulators + norm + fp16/bf16-split writes
    hipLaunchKernelGGL(normsplit_kernel, dim3(4128), dim3(256), 0, stream,
                       qm, sm, st, ws, qf, sf, stf, q_hi, q_lo, s_hi, s_lo);
    // 2: L2-direct streaming GEMM: A-pass (total_exp) + C-pass (den/num)
    hipLaunchKernelGGL(mfma_l2stream_kernel, dim3(544), dim3(256), 0, stream,
                       qf, sf, stf, total_exp, den, num);
    // 3: qs_loss (bf16x3 pos path) + finalize (ticketed last block)
    hipLaunchKernelGGL(qs2_kernel, dim3(256), dim3(128), 0, stream,
                       q_hi, q_lo, s_hi, s_lo, total_exp, den, num,
                       loss_acc, ticket, out);
}

// Round 10
// 178.914 us; speedup vs baseline: 1.0292x; 1.0292x over previous
//
#include <hip/hip_runtime.h>
#include <math.h>

// Problem constants
#define S_DIM 128
#define Q_DIM 64
#define P_DIM 64
#define D_DIM 256
#define NQ (S_DIM * Q_DIM)   // 8192 question rows
#define NS (S_DIM * P_DIM)   // 8192 sentence rows

typedef __attribute__((ext_vector_type(4))) float f32x4;
typedef __attribute__((ext_vector_type(8))) short bf16x8;
typedef __attribute__((ext_vector_type(8))) _Float16 f16x8;
typedef __attribute__((ext_vector_type(4))) _Float16 f16x4;

// ---------- helpers ----------
__device__ __forceinline__ unsigned short f2bf(float f) {
    unsigned int u = __float_as_uint(f);
    u = (u + 0x7fffu + ((u >> 16) & 1u)) >> 16;   // RNE (no NaN inputs here)
    return (unsigned short)u;
}
__device__ __forceinline__ float bf2f(unsigned short h) {
    return __uint_as_float(((unsigned int)h) << 16);
}
__device__ __forceinline__ void gload_lds16(const void* g, void* l) {
    __builtin_amdgcn_global_load_lds(
        (const __attribute__((address_space(1))) void*)g,
        (__attribute__((address_space(3))) void*)l, 16, 0, 0);
}

// ws layout:
//  floats [0, 8192)  total_exp (zeroed)
//  floats [8192,8320) den  [8320,8448) num  [8448,8450) loss_acc  [8452] ticket
//  halves from (ws+8704 floats):
//    qf [0,2097152)  sf [2097152,4194304)  stf [4194304,4227072)   (fp16, scaled)
//    q_hi @4718592  q_lo @6815744  s_hi @8912896  s_lo @11010048   (bf16, scaled)

// One wave per row: inv-norm; write fp16 scaled row (all tensors) and bf16
// hi/lo split (q,s only — consumed by the precision-sensitive qs2 pos path).
// exp(sim/TEMP) == exp2(dot of scaled rows) with per-row folded scale.
__global__ __launch_bounds__(256) void normsplit_kernel(
    const float* __restrict__ qm, const float* __restrict__ sm,
    const float* __restrict__ st, float* __restrict__ zero_region,
    _Float16* __restrict__ qf, _Float16* __restrict__ sf, _Float16* __restrict__ stf,
    unsigned short* __restrict__ q_hi, unsigned short* __restrict__ q_lo,
    unsigned short* __restrict__ s_hi, unsigned short* __restrict__ s_lo) {
    if (blockIdx.x < 34) {
        int i = blockIdx.x * 256 + threadIdx.x;
        if (i < 8456) zero_region[i] = 0.0f;
    }
    int row = blockIdx.x * 4 + (threadIdx.x >> 6);
    int lane = threadIdx.x & 63;
    const float* src;
    _Float16* fdst;
    unsigned short *hi = nullptr, *lo = nullptr;
    int r;
    if (row < NQ) {
        r = row; src = qm + (size_t)r * D_DIM; fdst = qf + (size_t)r * D_DIM;
        hi = q_hi + (size_t)r * D_DIM; lo = q_lo + (size_t)r * D_DIM;
    } else if (row < NQ + NS) {
        r = row - NQ; src = sm + (size_t)r * D_DIM; fdst = sf + (size_t)r * D_DIM;
        hi = s_hi + (size_t)r * D_DIM; lo = s_lo + (size_t)r * D_DIM;
    } else if (row < NQ + NS + S_DIM) {
        r = row - NQ - NS; src = st + (size_t)r * D_DIM; fdst = stf + (size_t)r * D_DIM;
    } else return;

    float4 v = reinterpret_cast<const float4*>(src)[lane];
    float ss = v.x * v.x + v.y * v.y + v.z * v.z + v.w * v.w;
    #pragma unroll
    for (int off = 32; off; off >>= 1) ss += __shfl_xor(ss, off);
    float inv = 1.0f / fmaxf(sqrtf(ss), 1e-12f);

    const float CF = sqrtf((1.0f / 0.07f) * 1.44269504088896f);
    float sc = inv * CF;
    float x[4] = {v.x * sc, v.y * sc, v.z * sc, v.w * sc};

    f16x4 fv;
    #pragma unroll
    for (int e = 0; e < 4; e++) fv[e] = (_Float16)x[e];
    reinterpret_cast<f16x4*>(fdst)[lane] = fv;

    if (hi) {
        ushort4 h, l;
        unsigned short* hp = &h.x; unsigned short* lp = &l.x;
        #pragma unroll
        for (int e = 0; e < 4; e++) {
            unsigned short hh = f2bf(x[e]);
            hp[e] = hh;
            lp[e] = f2bf(x[e] - bf2f(hh));
        }
        reinterpret_cast<ushort4*>(hi)[lane] = h;
        reinterpret_cast<ushort4*>(lo)[lane] = l;
    }
}

// Streaming fp16 MFMA GEMM + fused exp2/rowsum. 520 blocks x 256 threads
// (4 waves: 2 row-waves x 2 col-waves). R8 structure with 64 rows/wave:
// A-frags for the wave's 64 rows x FULL K=256 live in 128 regs (AGPR-parked,
// as R8's VGPR_Count=64 evidenced for the [2][8] case) -> per k-chunk each
// wave does 2 B ds_reads feeding 8 MFMA: B LDS-read traffic per 32KB tile is
// 64KB (2 row-waves) vs R8's 128KB (4 row-waves).
//  blocks [8,520): A-pass. block = 128 q-rows x 16 B-tiles (64 s-cols x K);
//    col-panel = (b-8)&7 -> XCD-local L2 residency.
//  blocks [0,8): C-pass. block = 128 st-rows x 16 q-col tiles; backfill first.
// Per tile-iter: stage next tile (8 gload_lds/wave, coalesced 16B dest) ->
// 8 k-chunks x {2 ds_read_b128 + 8 MFMA} -> __syncthreads (vmcnt(0) drain
// lands ~640cy after issue; near-free). 2-buffer ledger as R8 (reads of cur
// retire before end-of-iter barrier; next stage targets the other buffer).
// LDS B layout [chunk 8][kg 4][col 64][16B] — proven 0 bank conflicts (R6/R8).
__global__ __launch_bounds__(256, 2) void mfma_stream_kernel(
    const _Float16* __restrict__ qf, const _Float16* __restrict__ sf,
    const _Float16* __restrict__ stf,
    float* __restrict__ total_exp, float* __restrict__ den, float* __restrict__ num) {
    __shared__ __align__(16) char lds[2][32768];   // 64 KB -> 2 blocks/CU
    const int tid = threadIdx.x;
    const int w = tid >> 6, lane = tid & 63;
    const int lane15 = lane & 15, kg = lane >> 4;
    const int wr = w >> 1, wc = w & 1;   // 2 row-waves x 2 col-waves

    const bool cpass = (blockIdx.x < 8);
    const _Float16* A;
    const _Float16* B;
    int row0, colbase;
    if (cpass) {
        A = stf; B = qf; row0 = 0;
        colbase = (int)blockIdx.x * 1024;          // 8 q-col panels of 1024
    } else {
        const int b2 = (int)blockIdx.x - 8;        // 0..511
        A = qf; B = sf;
        row0 = (b2 >> 3) * 128;                    // 64 row-groups of 128
        colbase = (b2 & 7) * 1024;                 // col-panel == XCD (b2%8)
    }

    // A-fragments: this wave's 64 rows x K=256 in registers (128 regs).
    // 16x16x32 A layout: row = lane&15, k = (lane>>4)*8 + e (+ c*32 chunks).
    f16x8 af[4][8];
    {
        const _Float16* ap = A + (((size_t)(row0 + wr * 64 + lane15)) << 8) + kg * 8;
        #pragma unroll
        for (int mb = 0; mb < 4; mb++)
            #pragma unroll
            for (int c = 0; c < 8; c++)
                af[mb][c] = *reinterpret_cast<const f16x8*>(ap + mb * 16 * 256 + c * 32);
    }

    // Stage B-tile `t` into lds[buf]: per wave 8 x 1KB chunks, linear dest.
    // Dest byte o = w*8192 + i*1024 + lane*16 decodes to (chunk=o>>12,
    // kgs=(o>>10)&3, col=lane) -> source half-offset w*64 + i*8 in row col.
    auto STAGE = [&](int buf, int t) {
        const _Float16* src = B + (((size_t)(colbase + t * 64 + lane)) << 8) + w * 64;
        #pragma unroll
        for (int i = 0; i < 8; i++)
            gload_lds16(src + i * 8, &lds[buf][0] + w * 8192 + i * 1024);
    };

    float rs[4][4], nm[4][4];
    #pragma unroll
    for (int mb = 0; mb < 4; mb++)
        #pragma unroll
        for (int j = 0; j < 4; j++) { rs[mb][j] = 0.f; nm[mb][j] = 0.f; }

    STAGE(0, 0);
    __syncthreads();   // drains A-loads + tile0 stage together (one latency)

    for (int t = 0; t < 16; t++) {
        if (t + 1 < 16) STAGE((t + 1) & 1, t + 1);
        const char* Bb = &lds[t & 1][0];

        f32x4 acc[4][2];
        #pragma unroll
        for (int mb = 0; mb < 4; mb++) {
            acc[mb][0] = (f32x4){0.f, 0.f, 0.f, 0.f};
            acc[mb][1] = (f32x4){0.f, 0.f, 0.f, 0.f};
        }

        #pragma unroll
        for (int c = 0; c < 8; c++) {
            f16x8 bf0 = *reinterpret_cast<const f16x8*>(
                Bb + c * 4096 + kg * 1024 + (wc * 32 + lane15) * 16);
            f16x8 bf1 = *reinterpret_cast<const f16x8*>(
                Bb + c * 4096 + kg * 1024 + (wc * 32 + 16 + lane15) * 16);
            #pragma unroll
            for (int mb = 0; mb < 4; mb++) {
                acc[mb][0] = __builtin_amdgcn_mfma_f32_16x16x32_f16(af[mb][c], bf0, acc[mb][0], 0, 0, 0);
                acc[mb][1] = __builtin_amdgcn_mfma_f32_16x16x32_f16(af[mb][c], bf1, acc[mb][1], 0, 0, 0);
            }
        }

        // Per-tile epilogue in registers (C/D: col=lane15, row=(lane>>4)*4+j).
        #pragma unroll
        for (int mb = 0; mb < 4; mb++)
            #pragma unroll
            for (int j = 0; j < 4; j++) {
                float e0 = exp2f(acc[mb][0][j]);
                float e1 = exp2f(acc[mb][1][j]);
                rs[mb][j] += e0 + e1;
                if (cpass) {
                    const int grow = row0 + wr * 64 + mb * 16 + kg * 4 + j;
                    const int c0 = colbase + t * 64 + wc * 32 + lane15;
                    if ((c0 >> 6) == grow) nm[mb][j] += e0;
                    if (((c0 + 16) >> 6) == grow) nm[mb][j] += e1;
                }
            }
        __syncthreads();   // vmcnt(0): next-tile loads issued ~640cy ago; ~free
    }

    // Final: reduce over the 16-lane col group; one atomic per row per wave.
    #pragma unroll
    for (int mb = 0; mb < 4; mb++)
        #pragma unroll
        for (int j = 0; j < 4; j++) {
            float v = rs[mb][j], u = nm[mb][j];
            #pragma unroll
            for (int off = 1; off < 16; off <<= 1) {
                v += __shfl_xor(v, off);
                if (cpass) u += __shfl_xor(u, off);
            }
            if (lane15 == 0) {
                const int grow = row0 + wr * 64 + mb * 16 + kg * 4 + j;
                if (cpass) {
                    atomicAdd(&den[grow], v);
                    atomicAdd(&num[grow], u);
                } else {
                    atomicAdd(&total_exp[grow], v);
                }
            }
        }
}

// qs_loss + finalize. 256 blocks x 128 threads; block = half a section.
// pos/own_exp recomputed in bf16x3 (precision-sensitive path), straight from
// L2; all 16 A-frags preloaded for ILP. Last block (ticket) finalizes.
__global__ __launch_bounds__(128) void qs2_kernel(
    const unsigned short* __restrict__ q_hi, const unsigned short* __restrict__ q_lo,
    const unsigned short* __restrict__ s_hi, const unsigned short* __restrict__ s_lo,
    const float* __restrict__ total_exp, const float* __restrict__ den,
    const float* __restrict__ num, double* __restrict__ loss_acc,
    unsigned int* __restrict__ ticket, float* __restrict__ out) {
    const int s = blockIdx.x >> 1;
    const int tid = threadIdx.x;
    const int wid2 = ((blockIdx.x & 1) << 1) + (tid >> 6);   // 0..3 within section
    const int lane = tid & 63;
    __shared__ double wsum[2];
    __shared__ float w2[2];
    __shared__ unsigned int winner_s;

    const int arow = s * 64 + wid2 * 16 + (lane & 15);
    const int koff = (lane >> 4) * 8;

    bf16x8 ah[8], al[8];
    #pragma unroll
    for (int k8 = 0; k8 < 8; k8++) {
        ah[k8] = *reinterpret_cast<const bf16x8*>(&q_hi[(size_t)arow * D_DIM + k8 * 32 + koff]);
        al[k8] = *reinterpret_cast<const bf16x8*>(&q_lo[(size_t)arow * D_DIM + k8 * 32 + koff]);
    }

    f32x4 acc[4];
    #pragma unroll
    for (int n = 0; n < 4; n++) acc[n] = (f32x4){0.f, 0.f, 0.f, 0.f};
    #pragma unroll
    for (int n = 0; n < 4; n++) {
        const int brow = s * 64 + n * 16 + (lane & 15);
        #pragma unroll
        for (int k8 = 0; k8 < 8; k8++) {
            bf16x8 bh = *reinterpret_cast<const bf16x8*>(&s_hi[(size_t)brow * D_DIM + k8 * 32 + koff]);
            bf16x8 bl = *reinterpret_cast<const bf16x8*>(&s_lo[(size_t)brow * D_DIM + k8 * 32 + koff]);
            acc[n] = __builtin_amdgcn_mfma_f32_16x16x32_bf16(ah[k8], bh, acc[n], 0, 0, 0);
            acc[n] = __builtin_amdgcn_mfma_f32_16x16x32_bf16(ah[k8], bl, acc[n], 0, 0, 0);
            acc[n] = __builtin_amdgcn_mfma_f32_16x16x32_bf16(al[k8], bh, acc[n], 0, 0, 0);
        }
    }

    const float term2 = expf(-1.0f / 0.07f) * (float)(NS - 1);
    double lacc = 0.0;
    #pragma unroll
    for (int j = 0; j < 4; j++) {
        float e[4];
        float part = 0.0f;
        #pragma unroll
        for (int n = 0; n < 4; n++) { e[n] = exp2f(acc[n][j]); part += e[n]; }
        #pragma unroll
        for (int off = 1; off < 16; off <<= 1) part += __shfl_xor(part, off);
        const int trow = s * 64 + wid2 * 16 + (lane >> 4) * 4 + j;
        const float neg = total_exp[trow] - part;
        #pragma unroll
        for (int n = 0; n < 4; n++) {
            float posv = e[n];
            float t1 = fmaf(-0.1f, posv, neg / 0.9f);
            float Ng = fmaxf(fmaxf(t1, term2), 1e-8f);
            lacc += (double)(-logf(posv / (posv + Ng)));
        }
    }
    #pragma unroll
    for (int off = 1; off < 64; off <<= 1) lacc += __shfl_xor(lacc, off);
    if (lane == 0) wsum[tid >> 6] = lacc;
    __syncthreads();
    if (tid == 0) {
        atomicAdd(loss_acc, wsum[0] + wsum[1]);
        __threadfence();
        winner_s = atomicAdd(ticket, 1u);
    }
    __syncthreads();
    if (winner_s == 255) {
        __threadfence();   // acquire: all other blocks' loss atomics visible
        float l = -logf(num[tid] / den[tid]);   // tid = 0..127 = section
        #pragma unroll
        for (int off = 1; off < 64; off <<= 1) l += __shfl_xor(l, off);
        if ((tid & 63) == 0) w2[tid >> 6] = l;
        __syncthreads();
        if (tid == 0) out[0] = (float)(loss_acc[0] + (double)(w2[0] + w2[1]));
        // at_loss = -log(x/x) = 0 exactly; omitted.
    }
}

extern "C" void kernel_launch(void* const* d_in, const int* in_sizes, int n_in,
                              void* d_out, int out_size, void* d_ws, size_t ws_size,
                              hipStream_t stream) {
    const float* st = (const float*)d_in[1];   // [128,256]
    const float* qm = (const float*)d_in[2];   // [128,64,256]
    const float* sm = (const float*)d_in[3];   // [128,64,256]

    float* ws        = (float*)d_ws;
    float* total_exp = ws;
    float* den       = ws + 8192;
    float* num       = ws + 8320;
    double* loss_acc = (double*)(ws + 8448);
    unsigned int* ticket = (unsigned int*)(ws + 8452);
    _Float16* fbase = (_Float16*)(ws + 8704);
    _Float16* qf  = fbase;
    _Float16* sf  = fbase + 2097152;
    _Float16* stf = fbase + 4194304;
    unsigned short* b16 = (unsigned short*)fbase;
    unsigned short* q_hi = b16 + 4718592;
    unsigned short* q_lo = b16 + 6815744;
    unsigned short* s_hi = b16 + 8912896;
    unsigned short* s_lo = b16 + 11010048;
    float* out = (float*)d_out;

    // 1: zero accumulators + norm + fp16/bf16-split writes
    hipLaunchKernelGGL(normsplit_kernel, dim3(4128), dim3(256), 0, stream,
                       qm, sm, st, ws, qf, sf, stf, q_hi, q_lo, s_hi, s_lo);
    // 2: streaming GEMM (64 rows/wave): A-pass (total_exp) + C-pass (den/num)
    hipLaunchKernelGGL(mfma_stream_kernel, dim3(520), dim3(256), 0, stream,
                       qf, sf, stf, total_exp, den, num);
    // 3: qs_loss (bf16x3 pos path) + finalize (ticketed last block)
    hipLaunchKernelGGL(qs2_kernel, dim3(256), dim3(128), 0, stream,
                       q_hi, q_lo, s_hi, s_lo, total_exp, den, num,
                       loss_acc, ticket, out);
}

// Round 11
// 174.579 us; speedup vs baseline: 1.0547x; 1.0248x over previous
//
#include <hip/hip_runtime.h>
#include <math.h>

// Problem constants
#define S_DIM 128
#define Q_DIM 64
#define P_DIM 64
#define D_DIM 256
#define NQ (S_DIM * Q_DIM)   // 8192 question rows
#define NS (S_DIM * P_DIM)   // 8192 sentence rows

typedef __attribute__((ext_vector_type(4))) float f32x4;
typedef __attribute__((ext_vector_type(8))) short bf16x8;
typedef __attribute__((ext_vector_type(8))) _Float16 f16x8;
typedef __attribute__((ext_vector_type(4))) _Float16 f16x4;

// ---------- helpers ----------
__device__ __forceinline__ unsigned short f2bf(float f) {
    unsigned int u = __float_as_uint(f);
    u = (u + 0x7fffu + ((u >> 16) & 1u)) >> 16;   // RNE (no NaN inputs here)
    return (unsigned short)u;
}
__device__ __forceinline__ float bf2f(unsigned short h) {
    return __uint_as_float(((unsigned int)h) << 16);
}

// ws layout:
//  floats [0, 8192)  total_exp (zeroed)
//  floats [8192,8320) den  [8320,8448) num  [8448,8450) loss_acc  [8452] ticket
//  halves from (ws+8704 floats):
//    qft [0,2097152)      q in k-subtiled layout [k>>3][8192][k&7]
//    sft [2097152,4194304) s in k-subtiled layout [k>>3][8192][k&7]
//    stft[4194304,4227072) st in k-subtiled layout [k>>3][128][k&7]
//    q_hi @4718592  q_lo @6815744  s_hi @8912896  s_lo @11010048 (bf16 row-major)

// One wave per row: inv-norm; write fp16 scaled row into the k-subtiled global
// layout (element (k,row) -> [((k>>3)*NR + row)*8 + (k&7)]) and bf16 hi/lo
// row-major split (q,s only — consumed by the precision-sensitive qs2 path).
// exp(sim/TEMP) == exp2(dot of scaled rows) with per-row folded scale.
__global__ __launch_bounds__(256) void normsplit_kernel(
    const float* __restrict__ qm, const float* __restrict__ sm,
    const float* __restrict__ st, float* __restrict__ zero_region,
    _Float16* __restrict__ qft, _Float16* __restrict__ sft, _Float16* __restrict__ stft,
    unsigned short* __restrict__ q_hi, unsigned short* __restrict__ q_lo,
    unsigned short* __restrict__ s_hi, unsigned short* __restrict__ s_lo) {
    if (blockIdx.x < 34) {
        int i = blockIdx.x * 256 + threadIdx.x;
        if (i < 8456) zero_region[i] = 0.0f;
    }
    int row = blockIdx.x * 4 + (threadIdx.x >> 6);
    int lane = threadIdx.x & 63;
    const float* src;
    _Float16* ft;
    int NR, r;
    unsigned short *hi = nullptr, *lo = nullptr;
    if (row < NQ) {
        r = row; src = qm + (size_t)r * D_DIM; ft = qft; NR = NQ;
        hi = q_hi + (size_t)r * D_DIM; lo = q_lo + (size_t)r * D_DIM;
    } else if (row < NQ + NS) {
        r = row - NQ; src = sm + (size_t)r * D_DIM; ft = sft; NR = NS;
        hi = s_hi + (size_t)r * D_DIM; lo = s_lo + (size_t)r * D_DIM;
    } else if (row < NQ + NS + S_DIM) {
        r = row - NQ - NS; src = st + (size_t)r * D_DIM; ft = stft; NR = S_DIM;
    } else return;

    float4 v = reinterpret_cast<const float4*>(src)[lane];   // k = lane*4..+3
    float ss = v.x * v.x + v.y * v.y + v.z * v.z + v.w * v.w;
    #pragma unroll
    for (int off = 32; off; off >>= 1) ss += __shfl_xor(ss, off);
    float inv = 1.0f / fmaxf(sqrtf(ss), 1e-12f);

    const float CF = sqrtf((1.0f / 0.07f) * 1.44269504088896f);
    float sc = inv * CF;
    float x[4] = {v.x * sc, v.y * sc, v.z * sc, v.w * sc};

    // subtiled store: k = lane*4+e -> plane = lane>>1, sub = (lane&1)*4+e.
    f16x4 fv;
    #pragma unroll
    for (int e = 0; e < 4; e++) fv[e] = (_Float16)x[e];
    *reinterpret_cast<f16x4*>(ft + ((size_t)(lane >> 1) * NR + r) * 8 + (lane & 1) * 4) = fv;

    if (hi) {
        ushort4 h, l;
        unsigned short* hp = &h.x; unsigned short* lp = &l.x;
        #pragma unroll
        for (int e = 0; e < 4; e++) {
            unsigned short hh = f2bf(x[e]);
            hp[e] = hh;
            lp[e] = f2bf(x[e] - bf2f(hh));
        }
        reinterpret_cast<ushort4*>(hi)[lane] = h;
        reinterpret_cast<ushort4*>(lo)[lane] = l;
    }
}

// L2-direct streaming fp16 MFMA GEMM + fused exp2/rowsum. NO LDS, NO barriers,
// NO staging. 520 blocks x 256 threads (4 waves). Operands live in k-subtiled
// global layout, so every frag load is per-lane ((c*4+kg)*N + col)*16B:
// each quarter-wave reads 256B contiguous -> 16 fully-used cache lines per
// load (this fixes R9's 4x L2 over-fetch).
//  blocks [8,520): A-pass. wave = 64 q-rows x 512 s-cols. b2=blk-8: panel =
//    b2&7 (1024 s-cols, XCD-local L2), rg = (b2>>3)*2 + (w>>1), half = w&1.
//  blocks [0,8): C-pass. wave = 64 st-rows x 512 q-cols; backfilled first.
// Per wave: A-frags (64 rows x K=256, 128 regs, AGPR-parked — R8/R10 evidence)
// loaded once; then 16 col-groups x {16 coalesced B-loads + 32 MFMA + exp2
// epilogue in regs}. Loads never meet a barrier; compiler vmcnt pipelines.
// Atomics once per wave at the end.
__global__ __launch_bounds__(256, 2) void mfma_l2s_kernel(
    const _Float16* __restrict__ qft, const _Float16* __restrict__ sft,
    const _Float16* __restrict__ stft,
    float* __restrict__ total_exp, float* __restrict__ den, float* __restrict__ num) {
    const int tid = threadIdx.x;
    const int w = tid >> 6, lane = tid & 63;
    const int lane15 = lane & 15, kg = lane >> 4;

    const bool cpass = (blockIdx.x < 8);
    const _Float16* A;
    const _Float16* B;
    int row0, colbase, NRA;
    if (cpass) {
        A = stft; B = qft; NRA = S_DIM;
        row0 = (w >> 1) * 64;                                  // 2 rgs cover 128
        colbase = (int)blockIdx.x * 1024 + (w & 1) * 512;      // q-cols
    } else {
        const int b2 = (int)blockIdx.x - 8;                    // 0..511
        A = qft; B = sft; NRA = NQ;
        row0 = ((b2 >> 3) * 2 + (w >> 1)) * 64;                // 128 rgs of 64
        colbase = (b2 & 7) * 1024 + (w & 1) * 512;             // s-col panel==XCD
    }

    // A-fragments: wave's 64 rows x K=256 (128 regs; A operand row=lane15,
    // k=kg*8+e within chunk c). Subtiled addr: ((c*4+kg)*NRA + row)*8.
    f16x8 af[4][8];
    #pragma unroll
    for (int mb = 0; mb < 4; mb++)
        #pragma unroll
        for (int c = 0; c < 8; c++)
            af[mb][c] = *reinterpret_cast<const f16x8*>(
                A + ((size_t)(c * 4 + kg) * NRA + row0 + mb * 16 + lane15) * 8);

    float rs[4][4], nm[4][4];
    #pragma unroll
    for (int mb = 0; mb < 4; mb++)
        #pragma unroll
        for (int j = 0; j < 4; j++) { rs[mb][j] = 0.f; nm[mb][j] = 0.f; }

    for (int cg = 0; cg < 16; cg++) {
        const int c0 = colbase + cg * 32;
        f32x4 acc[4][2];
        #pragma unroll
        for (int mb = 0; mb < 4; mb++) {
            acc[mb][0] = (f32x4){0.f, 0.f, 0.f, 0.f};
            acc[mb][1] = (f32x4){0.f, 0.f, 0.f, 0.f};
        }
        #pragma unroll
        for (int c = 0; c < 8; c++) {
            const _Float16* p = B + ((size_t)(c * 4 + kg) * 8192 + c0 + lane15) * 8;
            f16x8 bf0 = *reinterpret_cast<const f16x8*>(p);
            f16x8 bf1 = *reinterpret_cast<const f16x8*>(p + 16 * 8);
            #pragma unroll
            for (int mb = 0; mb < 4; mb++) {
                acc[mb][0] = __builtin_amdgcn_mfma_f32_16x16x32_f16(af[mb][c], bf0, acc[mb][0], 0, 0, 0);
                acc[mb][1] = __builtin_amdgcn_mfma_f32_16x16x32_f16(af[mb][c], bf1, acc[mb][1], 0, 0, 0);
            }
        }
        // Epilogue in regs (C/D 16x16: col=lane15, row=kg*4+j within 16-tile).
        #pragma unroll
        for (int mb = 0; mb < 4; mb++)
            #pragma unroll
            for (int j = 0; j < 4; j++) {
                float e0 = exp2f(acc[mb][0][j]);
                float e1 = exp2f(acc[mb][1][j]);
                rs[mb][j] += e0 + e1;
                if (cpass) {
                    const int grow = row0 + mb * 16 + kg * 4 + j;
                    const int cc = c0 + lane15;
                    if ((cc >> 6) == grow) nm[mb][j] += e0;
                    if (((cc + 16) >> 6) == grow) nm[mb][j] += e1;
                }
            }
    }

    // Reduce over the 16-lane col group; one atomic per row per wave.
    #pragma unroll
    for (int mb = 0; mb < 4; mb++)
        #pragma unroll
        for (int j = 0; j < 4; j++) {
            float v = rs[mb][j], u = nm[mb][j];
            #pragma unroll
            for (int off = 1; off < 16; off <<= 1) {
                v += __shfl_xor(v, off);
                if (cpass) u += __shfl_xor(u, off);
            }
            if (lane15 == 0) {
                const int grow = row0 + mb * 16 + kg * 4 + j;
                if (cpass) {
                    atomicAdd(&den[grow], v);
                    atomicAdd(&num[grow], u);
                } else {
                    atomicAdd(&total_exp[grow], v);
                }
            }
        }
}

// qs_loss + finalize. 256 blocks x 128 threads; block = half a section.
// pos/own_exp recomputed in bf16x3 (precision-sensitive path), straight from
// L2; all 16 A-frags preloaded for ILP. Last block (ticket) finalizes.
__global__ __launch_bounds__(128) void qs2_kernel(
    const unsigned short* __restrict__ q_hi, const unsigned short* __restrict__ q_lo,
    const unsigned short* __restrict__ s_hi, const unsigned short* __restrict__ s_lo,
    const float* __restrict__ total_exp, const float* __restrict__ den,
    const float* __restrict__ num, double* __restrict__ loss_acc,
    unsigned int* __restrict__ ticket, float* __restrict__ out) {
    const int s = blockIdx.x >> 1;
    const int tid = threadIdx.x;
    const int wid2 = ((blockIdx.x & 1) << 1) + (tid >> 6);   // 0..3 within section
    const int lane = tid & 63;
    __shared__ double wsum[2];
    __shared__ float w2[2];
    __shared__ unsigned int winner_s;

    const int arow = s * 64 + wid2 * 16 + (lane & 15);
    const int koff = (lane >> 4) * 8;

    bf16x8 ah[8], al[8];
    #pragma unroll
    for (int k8 = 0; k8 < 8; k8++) {
        ah[k8] = *reinterpret_cast<const bf16x8*>(&q_hi[(size_t)arow * D_DIM + k8 * 32 + koff]);
        al[k8] = *reinterpret_cast<const bf16x8*>(&q_lo[(size_t)arow * D_DIM + k8 * 32 + koff]);
    }

    f32x4 acc[4];
    #pragma unroll
    for (int n = 0; n < 4; n++) acc[n] = (f32x4){0.f, 0.f, 0.f, 0.f};
    #pragma unroll
    for (int n = 0; n < 4; n++) {
        const int brow = s * 64 + n * 16 + (lane & 15);
        #pragma unroll
        for (int k8 = 0; k8 < 8; k8++) {
            bf16x8 bh = *reinterpret_cast<const bf16x8*>(&s_hi[(size_t)brow * D_DIM + k8 * 32 + koff]);
            bf16x8 bl = *reinterpret_cast<const bf16x8*>(&s_lo[(size_t)brow * D_DIM + k8 * 32 + koff]);
            acc[n] = __builtin_amdgcn_mfma_f32_16x16x32_bf16(ah[k8], bh, acc[n], 0, 0, 0);
            acc[n] = __builtin_amdgcn_mfma_f32_16x16x32_bf16(ah[k8], bl, acc[n], 0, 0, 0);
            acc[n] = __builtin_amdgcn_mfma_f32_16x16x32_bf16(al[k8], bh, acc[n], 0, 0, 0);
        }
    }

    const float term2 = expf(-1.0f / 0.07f) * (float)(NS - 1);
    double lacc = 0.0;
    #pragma unroll
    for (int j = 0; j < 4; j++) {
        float e[4];
        float part = 0.0f;
        #pragma unroll
        for (int n = 0; n < 4; n++) { e[n] = exp2f(acc[n][j]); part += e[n]; }
        #pragma unroll
        for (int off = 1; off < 16; off <<= 1) part += __shfl_xor(part, off);
        const int trow = s * 64 + wid2 * 16 + (lane >> 4) * 4 + j;
        const float neg = total_exp[trow] - part;
        #pragma unroll
        for (int n = 0; n < 4; n++) {
            float posv = e[n];
            float t1 = fmaf(-0.1f, posv, neg / 0.9f);
            float Ng = fmaxf(fmaxf(t1, term2), 1e-8f);
            lacc += (double)(-logf(posv / (posv + Ng)));
        }
    }
    #pragma unroll
    for (int off = 1; off < 64; off <<= 1) lacc += __shfl_xor(lacc, off);
    if (lane == 0) wsum[tid >> 6] = lacc;
    __syncthreads();
    if (tid == 0) {
        atomicAdd(loss_acc, wsum[0] + wsum[1]);
        __threadfence();
        winner_s = atomicAdd(ticket, 1u);
    }
    __syncthreads();
    if (winner_s == 255) {
        __threadfence();   // acquire: all other blocks' loss atomics visible
        float l = -logf(num[tid] / den[tid]);   // tid = 0..127 = section
        #pragma unroll
        for (int off = 1; off < 64; off <<= 1) l += __shfl_xor(l, off);
        if ((tid & 63) == 0) w2[tid >> 6] = l;
        __syncthreads();
        if (tid == 0) out[0] = (float)(loss_acc[0] + (double)(w2[0] + w2[1]));
        // at_loss = -log(x/x) = 0 exactly; omitted.
    }
}

extern "C" void kernel_launch(void* const* d_in, const int* in_sizes, int n_in,
                              void* d_out, int out_size, void* d_ws, size_t ws_size,
                              hipStream_t stream) {
    const float* st = (const float*)d_in[1];   // [128,256]
    const float* qm = (const float*)d_in[2];   // [128,64,256]
    const float* sm = (const float*)d_in[3];   // [128,64,256]

    float* ws        = (float*)d_ws;
    float* total_exp = ws;
    float* den       = ws + 8192;
    float* num       = ws + 8320;
    double* loss_acc = (double*)(ws + 8448);
    unsigned int* ticket = (unsigned int*)(ws + 8452);
    _Float16* fbase = (_Float16*)(ws + 8704);
    _Float16* qft  = fbase;
    _Float16* sft  = fbase + 2097152;
    _Float16* stft = fbase + 4194304;
    unsigned short* b16 = (unsigned short*)fbase;
    unsigned short* q_hi = b16 + 4718592;
    unsigned short* q_lo = b16 + 6815744;
    unsigned short* s_hi = b16 + 8912896;
    unsigned short* s_lo = b16 + 11010048;
    float* out = (float*)d_out;

    // 1: zero accumulators + norm + subtiled-fp16/bf16-split writes
    hipLaunchKernelGGL(normsplit_kernel, dim3(4128), dim3(256), 0, stream,
                       qm, sm, st, ws, qft, sft, stft, q_hi, q_lo, s_hi, s_lo);
    // 2: L2-direct coalesced streaming GEMM: A-pass (total_exp) + C-pass (den/num)
    hipLaunchKernelGGL(mfma_l2s_kernel, dim3(520), dim3(256), 0, stream,
                       qft, sft, stft, total_exp, den, num);
    // 3: qs_loss (bf16x3 pos path) + finalize (ticketed last block)
    hipLaunchKernelGGL(qs2_kernel, dim3(256), dim3(128), 0, stream,
                       q_hi, q_lo, s_hi, s_lo, total_exp, den, num,
                       loss_acc, ticket, out);
}

// Round 12
// 160.568 us; speedup vs baseline: 1.1468x; 1.0873x over previous
//
#include <hip/hip_runtime.h>
#include <math.h>

// Problem constants
#define S_DIM 128
#define Q_DIM 64
#define P_DIM 64
#define D_DIM 256
#define NQ (S_DIM * Q_DIM)   // 8192 question rows
#define NS (S_DIM * P_DIM)   // 8192 sentence rows

typedef __attribute__((ext_vector_type(4))) float f32x4;
typedef __attribute__((ext_vector_type(8))) short bf16x8;
typedef __attribute__((ext_vector_type(8))) _Float16 f16x8;
typedef __attribute__((ext_vector_type(4))) _Float16 f16x4;

// ---------- helpers ----------
__device__ __forceinline__ unsigned short f2bf(float f) {
    unsigned int u = __float_as_uint(f);
    u = (u + 0x7fffu + ((u >> 16) & 1u)) >> 16;   // RNE (no NaN inputs here)
    return (unsigned short)u;
}
__device__ __forceinline__ float bf2f(unsigned short h) {
    return __uint_as_float(((unsigned int)h) << 16);
}
__device__ __forceinline__ void gload_lds16(const void* g, void* l) {
    __builtin_amdgcn_global_load_lds(
        (const __attribute__((address_space(1))) void*)g,
        (__attribute__((address_space(3))) void*)l, 16, 0, 0);
}

// ws layout:
//  floats [0, 8192)  total_exp (zeroed)
//  floats [8192,8320) den  [8320,8448) num  [8448,8450) loss_acc  [8452] ticket
//  halves from (ws+8704 floats):
//    qf [0,2097152)  sf [2097152,4194304)  stf [4194304,4227072)  (fp16 row-major)
//    q_hi @4718592  q_lo @6815744  s_hi @8912896  s_lo @11010048
//      (bf16, K-SUBTILED layout [k>>3][row][k&7] for coalesced qs2 frag loads)

// One wave per row: inv-norm; write fp16 scaled row (row-major, all tensors)
// and bf16 hi/lo split in k-subtiled layout (q,s only — qs2's pos path).
// exp(sim/TEMP) == exp2(dot of scaled rows) with per-row folded scale.
__global__ __launch_bounds__(256) void normsplit_kernel(
    const float* __restrict__ qm, const float* __restrict__ sm,
    const float* __restrict__ st, float* __restrict__ zero_region,
    _Float16* __restrict__ qf, _Float16* __restrict__ sf, _Float16* __restrict__ stf,
    unsigned short* __restrict__ q_hi, unsigned short* __restrict__ q_lo,
    unsigned short* __restrict__ s_hi, unsigned short* __restrict__ s_lo) {
    if (blockIdx.x < 34) {
        int i = blockIdx.x * 256 + threadIdx.x;
        if (i < 8456) zero_region[i] = 0.0f;
    }
    int row = blockIdx.x * 4 + (threadIdx.x >> 6);
    int lane = threadIdx.x & 63;
    const float* src;
    _Float16* fdst;
    unsigned short *hi = nullptr, *lo = nullptr;
    int r;
    if (row < NQ) {
        r = row; src = qm + (size_t)r * D_DIM; fdst = qf + (size_t)r * D_DIM;
        hi = q_hi; lo = q_lo;
    } else if (row < NQ + NS) {
        r = row - NQ; src = sm + (size_t)r * D_DIM; fdst = sf + (size_t)r * D_DIM;
        hi = s_hi; lo = s_lo;
    } else if (row < NQ + NS + S_DIM) {
        r = row - NQ - NS; src = st + (size_t)r * D_DIM; fdst = stf + (size_t)r * D_DIM;
    } else return;

    float4 v = reinterpret_cast<const float4*>(src)[lane];   // k = lane*4..+3
    float ss = v.x * v.x + v.y * v.y + v.z * v.z + v.w * v.w;
    #pragma unroll
    for (int off = 32; off; off >>= 1) ss += __shfl_xor(ss, off);
    float inv = 1.0f / fmaxf(sqrtf(ss), 1e-12f);

    const float CF = sqrtf((1.0f / 0.07f) * 1.44269504088896f);
    float sc = inv * CF;
    float x[4] = {v.x * sc, v.y * sc, v.z * sc, v.w * sc};

    f16x4 fv;
    #pragma unroll
    for (int e = 0; e < 4; e++) fv[e] = (_Float16)x[e];
    reinterpret_cast<f16x4*>(fdst)[lane] = fv;

    if (hi) {
        ushort4 h, l;
        unsigned short* hp = &h.x; unsigned short* lp = &l.x;
        #pragma unroll
        for (int e = 0; e < 4; e++) {
            unsigned short hh = f2bf(x[e]);
            hp[e] = hh;
            lp[e] = f2bf(x[e] - bf2f(hh));
        }
        // k-subtiled store: k = lane*4+e -> plane = lane>>1, sub = (lane&1)*4+e.
        const size_t o = ((size_t)(lane >> 1) * 8192 + r) * 8 + (lane & 1) * 4;
        *reinterpret_cast<ushort4*>(hi + o) = h;
        *reinterpret_cast<ushort4*>(lo + o) = l;
    }
}

// Streaming fp16 MFMA GEMM + fused exp2/rowsum (R8 structure, verbatim).
// 576 blocks x 512 threads (8 waves: 4 row-waves x 2 col-waves).
//  blocks [64,576): A-pass. Block owns 128 q-rows (A-frags for FULL K=256 in
//    VGPRs/AGPRs), streams 16 B-tiles (64 s-cols x K, 32 KB) from its
//    XCD-local column panel (colgroup = (b-64)&7 -> L2-resident).
//  blocks [0,64): C-pass. Same loop, A=stf (128 st-rows), 2 q-col tiles each;
//    short blocks dispatched first so they backfill the schedule.
// Per tile-iter: stage next tile (4 gload_lds/wave) -> 8 k-chunks x {2
// ds_read_b128 + 4 MFMA} -> __syncthreads (vmcnt(0) drain issued ~600cy after
// the loads; near-free). 2-buffer ledger: buf[(t+1)&1] staged at iter t was
// last read at iter t-1; buf[t&1] staged at t-1 drained by t-1's barrier.
// LDS B layout [chunk 8][kg 4][col 64][16B] — 0 bank conflicts (measured R6/R8).
__global__ __launch_bounds__(512, 4) void mfma_stream_kernel(
    const _Float16* __restrict__ qf, const _Float16* __restrict__ sf,
    const _Float16* __restrict__ stf,
    float* __restrict__ total_exp, float* __restrict__ den, float* __restrict__ num) {
    __shared__ __align__(16) char lds[2][32768];   // 64 KB -> 2 blocks/CU
    const int tid = threadIdx.x;
    const int wid = tid >> 6, lane = tid & 63;
    const int lane15 = lane & 15, kg = lane >> 4;
    const int wr = wid >> 1, wc = wid & 1;   // 4 row-waves x 2 col-waves

    const bool cpass = (blockIdx.x < 64);
    const _Float16* A;
    const _Float16* B;
    int row0, colbase, ntiles;
    if (cpass) {
        A = stf; B = qf; row0 = 0;
        colbase = (int)blockIdx.x * 128; ntiles = 2;
    } else {
        const int b = (int)blockIdx.x - 64;
        A = qf; B = sf;
        row0 = (b >> 3) * 128;            // 64 row-blocks
        colbase = (b & 7) * 1024;         // col-group == XCD (b%8)
    }
    if (!cpass) ntiles = 16;

    // A-fragments for this wave's 32 rows, full K, in registers (64 VGPR).
    f16x8 af[2][8];
    {
        const _Float16* ap = A + (((size_t)(row0 + wr * 32 + lane15)) << 8) + kg * 8;
        #pragma unroll
        for (int mb = 0; mb < 2; mb++)
            #pragma unroll
            for (int c = 0; c < 8; c++)
                af[mb][c] = *reinterpret_cast<const f16x8*>(ap + mb * 16 * 256 + c * 32);
    }

    // Stage B-tile `t` into lds[buf]: per wave 4 x 1KB chunks. Linear dest byte
    // o = wid*4096 + i*1024 + lane*16 decodes to (chunk=wid, kg=i, col=lane).
    auto STAGE = [&](int buf, int t) {
        const _Float16* src = B + (((size_t)(colbase + t * 64 + lane)) << 8) + wid * 32;
        #pragma unroll
        for (int i = 0; i < 4; i++)
            gload_lds16(src + i * 8, &lds[buf][0] + wid * 4096 + i * 1024);
    };

    float rs[2][4] = {{0.f, 0.f, 0.f, 0.f}, {0.f, 0.f, 0.f, 0.f}};
    float nm[2][4] = {{0.f, 0.f, 0.f, 0.f}, {0.f, 0.f, 0.f, 0.f}};

    STAGE(0, 0);
    __syncthreads();   // drains A-loads + tile0 stage together (one latency)

    for (int t = 0; t < ntiles; t++) {
        if (t + 1 < ntiles) STAGE((t + 1) & 1, t + 1);
        const char* Bb = &lds[t & 1][0];

        f32x4 acc[2][2];
        #pragma unroll
        for (int mb = 0; mb < 2; mb++)
            #pragma unroll
            for (int n = 0; n < 2; n++) acc[mb][n] = (f32x4){0.f, 0.f, 0.f, 0.f};

        #pragma unroll
        for (int c = 0; c < 8; c++) {
            f16x8 bf[2];
            #pragma unroll
            for (int n = 0; n < 2; n++)
                bf[n] = *reinterpret_cast<const f16x8*>(
                    Bb + c * 4096 + kg * 1024 + (wc * 32 + n * 16 + lane15) * 16);
            #pragma unroll
            for (int mb = 0; mb < 2; mb++)
                #pragma unroll
                for (int n = 0; n < 2; n++)
                    acc[mb][n] = __builtin_amdgcn_mfma_f32_16x16x32_f16(
                        af[mb][c], bf[n], acc[mb][n], 0, 0, 0);
        }

        // Per-tile epilogue in registers (C/D: col=lane15, row=(lane>>4)*4+j).
        #pragma unroll
        for (int mb = 0; mb < 2; mb++)
            #pragma unroll
            for (int j = 0; j < 4; j++) {
                const int grow = row0 + wr * 32 + mb * 16 + kg * 4 + j;
                #pragma unroll
                for (int n = 0; n < 2; n++) {
                    float e = exp2f(acc[mb][n][j]);
                    rs[mb][j] += e;
                    if (cpass) {
                        int col = colbase + t * 64 + wc * 32 + n * 16 + lane15;
                        if ((col >> 6) == grow) nm[mb][j] += e;
                    }
                }
            }
        __syncthreads();   // vmcnt(0): next-tile loads issued ~600cy ago; free
    }

    // Final: reduce over the 16-lane col group, one atomic per row.
    #pragma unroll
    for (int mb = 0; mb < 2; mb++)
        #pragma unroll
        for (int j = 0; j < 4; j++) {
            float v = rs[mb][j], w2 = nm[mb][j];
            #pragma unroll
            for (int off = 1; off < 16; off <<= 1) {
                v += __shfl_xor(v, off);
                if (cpass) w2 += __shfl_xor(w2, off);
            }
            if (lane15 == 0) {
                const int grow = row0 + wr * 32 + mb * 16 + kg * 4 + j;
                if (cpass) {
                    atomicAdd(&den[grow], v);
                    atomicAdd(&num[grow], w2);
                } else {
                    atomicAdd(&total_exp[grow], v);
                }
            }
        }
}

// qs_loss + finalize. 256 blocks x 128 threads; block = half a section.
// pos/own_exp recomputed in bf16x3 (precision-sensitive path) from the
// K-SUBTILED hi/lo tensors: frag load per lane = base + lane15*16B ->
// quarter-wave reads 256B contiguous (fixes the 512B-stride over-fetch).
// Element mapping identical to row-major version: ah[k8][e] = k8*32+kg*8+e.
// Last block (ticket) finalizes.
__global__ __launch_bounds__(128) void qs2_kernel(
    const unsigned short* __restrict__ q_hi, const unsigned short* __restrict__ q_lo,
    const unsigned short* __restrict__ s_hi, const unsigned short* __restrict__ s_lo,
    const float* __restrict__ total_exp, const float* __restrict__ den,
    const float* __restrict__ num, double* __restrict__ loss_acc,
    unsigned int* __restrict__ ticket, float* __restrict__ out) {
    const int s = blockIdx.x >> 1;
    const int tid = threadIdx.x;
    const int wid2 = ((blockIdx.x & 1) << 1) + (tid >> 6);   // 0..3 within section
    const int lane = tid & 63;
    const int lane15 = lane & 15, kg = lane >> 4;
    __shared__ double wsum[2];
    __shared__ float w2[2];
    __shared__ unsigned int winner_s;

    const int arow = s * 64 + wid2 * 16 + lane15;

    bf16x8 ah[8], al[8];
    #pragma unroll
    for (int k8 = 0; k8 < 8; k8++) {
        const size_t o = ((size_t)(k8 * 4 + kg) * 8192 + arow) * 8;
        ah[k8] = *reinterpret_cast<const bf16x8*>(q_hi + o);
        al[k8] = *reinterpret_cast<const bf16x8*>(q_lo + o);
    }

    f32x4 acc[4];
    #pragma unroll
    for (int n = 0; n < 4; n++) acc[n] = (f32x4){0.f, 0.f, 0.f, 0.f};
    #pragma unroll
    for (int n = 0; n < 4; n++) {
        const int brow = s * 64 + n * 16 + lane15;
        #pragma unroll
        for (int k8 = 0; k8 < 8; k8++) {
            const size_t o = ((size_t)(k8 * 4 + kg) * 8192 + brow) * 8;
            bf16x8 bh = *reinterpret_cast<const bf16x8*>(s_hi + o);
            bf16x8 bl = *reinterpret_cast<const bf16x8*>(s_lo + o);
            acc[n] = __builtin_amdgcn_mfma_f32_16x16x32_bf16(ah[k8], bh, acc[n], 0, 0, 0);
            acc[n] = __builtin_amdgcn_mfma_f32_16x16x32_bf16(ah[k8], bl, acc[n], 0, 0, 0);
            acc[n] = __builtin_amdgcn_mfma_f32_16x16x32_bf16(al[k8], bh, acc[n], 0, 0, 0);
        }
    }

    const float term2 = expf(-1.0f / 0.07f) * (float)(NS - 1);
    double lacc = 0.0;
    #pragma unroll
    for (int j = 0; j < 4; j++) {
        float e[4];
        float part = 0.0f;
        #pragma unroll
        for (int n = 0; n < 4; n++) { e[n] = exp2f(acc[n][j]); part += e[n]; }
        #pragma unroll
        for (int off = 1; off < 16; off <<= 1) part += __shfl_xor(part, off);
        const int trow = s * 64 + wid2 * 16 + kg * 4 + j;
        const float neg = total_exp[trow] - part;
        #pragma unroll
        for (int n = 0; n < 4; n++) {
            float posv = e[n];
            float t1 = fmaf(-0.1f, posv, neg / 0.9f);
            float Ng = fmaxf(fmaxf(t1, term2), 1e-8f);
            lacc += (double)(-logf(posv / (posv + Ng)));
        }
    }
    #pragma unroll
    for (int off = 1; off < 64; off <<= 1) lacc += __shfl_xor(lacc, off);
    if (lane == 0) wsum[tid >> 6] = lacc;
    __syncthreads();
    if (tid == 0) {
        atomicAdd(loss_acc, wsum[0] + wsum[1]);
        __threadfence();
        winner_s = atomicAdd(ticket, 1u);
    }
    __syncthreads();
    if (winner_s == 255) {
        __threadfence();   // acquire: all other blocks' loss atomics visible
        float l = -logf(num[tid] / den[tid]);   // tid = 0..127 = section
        #pragma unroll
        for (int off = 1; off < 64; off <<= 1) l += __shfl_xor(l, off);
        if ((tid & 63) == 0) w2[tid >> 6] = l;
        __syncthreads();
        if (tid == 0) out[0] = (float)(loss_acc[0] + (double)(w2[0] + w2[1]));
        // at_loss = -log(x/x) = 0 exactly; omitted.
    }
}

extern "C" void kernel_launch(void* const* d_in, const int* in_sizes, int n_in,
                              void* d_out, int out_size, void* d_ws, size_t ws_size,
                              hipStream_t stream) {
    const float* st = (const float*)d_in[1];   // [128,256]
    const float* qm = (const float*)d_in[2];   // [128,64,256]
    const float* sm = (const float*)d_in[3];   // [128,64,256]

    float* ws        = (float*)d_ws;
    float* total_exp = ws;
    float* den       = ws + 8192;
    float* num       = ws + 8320;
    double* loss_acc = (double*)(ws + 8448);
    unsigned int* ticket = (unsigned int*)(ws + 8452);
    _Float16* fbase = (_Float16*)(ws + 8704);
    _Float16* qf  = fbase;
    _Float16* sf  = fbase + 2097152;
    _Float16* stf = fbase + 4194304;
    unsigned short* b16 = (unsigned short*)fbase;
    unsigned short* q_hi = b16 + 4718592;
    unsigned short* q_lo = b16 + 6815744;
    unsigned short* s_hi = b16 + 8912896;
    unsigned short* s_lo = b16 + 11010048;
    float* out = (float*)d_out;

    // 1: zero accumulators + norm + fp16 row-major + bf16 subtiled writes
    hipLaunchKernelGGL(normsplit_kernel, dim3(4128), dim3(256), 0, stream,
                       qm, sm, st, ws, qf, sf, stf, q_hi, q_lo, s_hi, s_lo);
    // 2: streaming GEMM (R8 structure): A-pass (total_exp) + C-pass (den/num)
    hipLaunchKernelGGL(mfma_stream_kernel, dim3(576), dim3(512), 0, stream,
                       qf, sf, stf, total_exp, den, num);
    // 3: qs_loss (bf16x3 pos path, coalesced subtiled loads) + finalize
    hipLaunchKernelGGL(qs2_kernel, dim3(256), dim3(128), 0, stream,
                       q_hi, q_lo, s_hi, s_lo, total_exp, den, num,
                       loss_acc, ticket, out);
}